// Round 21
// baseline (87.574 us; speedup 1.0000x reference)
//
#include <hip/hip_runtime.h>
#include <hip/hip_fp16.h>
#include <math.h>

// LeNet-ish forward, fp32 compute, B=8192.
// conv1+pool = stride-2 6x6 conv (w6 = W1 (*) ones(2,2), /4 at use).
// S1 fp16 (r18); conv1 1-ch/thread (r19).
// r20/r21: conv2 FUSED into k_fc (h2 never in global; h2t written
// transposed straight into LDS). r21 FIX: FC2 weight stage goes at
// arena[0..10560) over dead h2t+wt -- r20 put it at +5760 which overlapped
// LIVE g1t (13952..16112) and corrupted FC2's input.
//
// ws: [w6 4KB][w2q 32KB][S1h: B*1328 fp16]

__device__ __forceinline__ float sigf(float v) {
    return 1.0f / (1.0f + __expf(-v));
}

// --- K0: prep. w6[ky][c][8] from W1; w2q repack. ---
__global__ void k_prep(const float* __restrict__ W1, const float* __restrict__ W2,
                       float* __restrict__ w6, float* __restrict__ w2q) {
    int i = blockIdx.x * 256 + threadIdx.x;
    if (i < 5000) {
        int kx = i % 5, t = i / 5;
        int ky = t % 5, t2 = t / 5;
        int ic = t2 % 10, c = t2 / 10;
        w2q[((ic * 5 + ky) * 20 + c) * 5 + kx] = W2[i];
    }
    int k = i - 5000;
    if (k >= 0 && k < 480) {
        int kx = k % 8, t = k / 8;
        int c = t % 10, ky = t / 10;
        float v = 0.f;
        if (kx < 6) {
            for (int dy = 0; dy < 2; ++dy)
                for (int dx = 0; dx < 2; ++dx) {
                    int sy = ky - dy, sx = kx - dx;
                    if (sy >= 0 && sy < 5 && sx >= 0 && sx < 5)
                        v += W1[c * 25 + sy * 5 + sx];
                }
        }
        w6[k] = v;
    }
}

#define S1IM 1328  // per-image stride in halves (2656 B)

// --- K1: conv1(6x6 s2) + sigmoid + 2x2 window-sum -> S1h fp16 (r19). ---
__global__ __launch_bounds__(512) void k_conv1(
    const float* __restrict__ x, const float* __restrict__ w6g,
    const float* __restrict__ b1, __half* __restrict__ S1h) {
    __shared__ float4 XR[4 * 224];  // 14336 B, XOR-swizzled
    __shared__ float wq1[480];      // [ky6][ch10][8]
    __shared__ float bs1[10];

    const int tid = threadIdx.x;
    const long img0 = (long)blockIdx.x * 4;

    {
        const float4* xg = (const float4*)(x + img0 * 784);
        for (int i = tid; i < 784; i += 512) {
            int im = i / 196, j = i % 196, r = j / 7, kk = j % 7;
            XR[im * 224 + r * 8 + (kk ^ ((r >> 1) & 7))] = xg[i];
        }
    }
    if (tid < 480) wq1[tid] = w6g[tid];
    else if (tid < 490) bs1[tid - 480] = b1[tid - 480];
    __syncthreads();

    const int w = tid >> 6, l = tid & 63;
    const int im = w >> 1, chbase = (w & 1) * 5;
    const long img = img0 + im;
    if (l < 60) {
        const int c = l / 12, py = l % 12;
        const int ch = chbase + c;
        float acc[12];
#pragma unroll
        for (int p = 0; p < 12; ++p) acc[p] = 0.f;

        const float4* xr = &XR[im * 224];
#pragma unroll
        for (int ky = 0; ky < 6; ++ky) {
            const int r = 2 * py + ky;
            const int hsh = (r >> 1) & 7;
            const int base = r * 8;
            union { float4 v[7]; float f[28]; } R;
#pragma unroll
            for (int q = 0; q < 7; ++q) R.v[q] = xr[base + (q ^ hsh)];
            union { float4 v[2]; float f[8]; } W;
            const float* wb = &wq1[(ky * 10 + ch) * 8];
            W.v[0] = *(const float4*)(wb);
            W.v[1] = *(const float4*)(wb + 4);
#pragma unroll
            for (int kx = 0; kx < 6; ++kx) {
                const float wv = W.f[kx];
#pragma unroll
                for (int px = 0; px < 12; ++px)
                    acc[px] += R.f[2 * px + kx] * wv;
            }
        }

        float h[12];
#pragma unroll
        for (int px = 0; px < 12; ++px)
            h[px] = sigf(acc[px] * 0.25f + bs1[ch]);
        float hh[11];
#pragma unroll
        for (int t = 0; t < 11; ++t) hh[t] = h[t] + h[t + 1];
        float o[12];
#pragma unroll
        for (int t = 0; t < 11; ++t)
            o[t] = hh[t] + __shfl_down(hh[t], 1, 64);
        o[11] = 0.f;
        if (py < 11) {
            union { __half hs[12]; uint2 u2[3]; } P;
#pragma unroll
            for (int t = 0; t < 12; ++t) P.hs[t] = __float2half(o[t]);
            __half* sp = S1h + img * S1IM + ch * 132 + py * 12;
            ((uint2*)sp)[0] = P.u2[0];
            ((uint2*)sp)[1] = P.u2[1];
            ((uint2*)sp)[2] = P.u2[2];
        }
    }
}

// --- K2: conv2 + FC chain fused. 16 img/block, grid B/16=512, 256 thr. ---
#define TSTR 18
__global__ __launch_bounds__(256) void k_fc(
    const __half* __restrict__ S1h, const float* __restrict__ w2qg,
    const float* __restrict__ b2, const float* __restrict__ L1,
    const float* __restrict__ Lb1, const float* __restrict__ L2,
    const float* __restrict__ Lb2, const float* __restrict__ L3,
    const float* __restrict__ Lb3, float* __restrict__ out) {
    __shared__ float arena[18480];   // 73920 B
    float* h2t = arena;              // [320][18]  = 5760
    float* wt  = arena + 5760;       // [2][32][128] = 8192 (FC1)
    float* g1t = arena + 13952;      // [120][18] = 2160
    float* g2t = arena + 16112;      // [84][18]  = 1512
    float* L3s = arena + 17624;      // 840 + 10

    const int tid = threadIdx.x;
    const long img0 = (long)blockIdx.x * 16;

    // ---- Phase A: conv2 + pool + sigmoid -> h2t (transposed, in LDS) ----
    for (int u = tid; u < 640; u += 256) {
        const int im = u & 15, r = u >> 4;
        const int cg = __builtin_amdgcn_readfirstlane(r / 8);
        const int py = (r >> 1) & 3, xh = r & 1;

        float acc[4][2];
#pragma unroll
        for (int a = 0; a < 4; ++a) { acc[a][0] = 0.f; acc[a][1] = 0.f; }

        const __half* s1 = S1h + (img0 + im) * S1IM;
        const float* wg = w2qg + cg * 20;
        for (int ic = 0; ic < 10; ++ic) {
#pragma unroll
            for (int ky = 0; ky < 5; ++ky) {
                const __half* rp = s1 + ic * 132 + (2 * py + ky) * 12 + xh * 4;
                union { uint2 u2; __half2 h2v[2]; } A, Bv;
                A.u2 = *(const uint2*)(rp);
                Bv.u2 = *(const uint2*)(rp + 4);
                float R[8];
                float2 f0 = __half22float2(A.h2v[0]);
                float2 f1 = __half22float2(A.h2v[1]);
                float2 f2 = __half22float2(Bv.h2v[0]);
                float2 f3 = __half22float2(Bv.h2v[1]);
                R[0] = f0.x; R[1] = f0.y; R[2] = f1.x; R[3] = f1.y;
                R[4] = f2.x; R[5] = f2.y; R[6] = f3.x; R[7] = f3.y;
                const float* wrow = wg + (ic * 5 + ky) * 100;
#pragma unroll
                for (int cc = 0; cc < 4; ++cc)
#pragma unroll
                    for (int kx = 0; kx < 5; ++kx) {
                        const float wv = wrow[cc * 5 + kx];  // s_load (uniform)
                        acc[cc][0] += R[kx] * wv;
                        acc[cc][1] += R[2 + kx] * wv;
                    }
            }
        }

#pragma unroll
        for (int cc = 0; cc < 4; ++cc) {
            const float bv = b2[cg * 4 + cc];  // uniform s_load
            const int feat = (cg * 4 + cc) * 16 + py * 4 + xh * 2;
            h2t[feat * TSTR + im] = sigf(acc[cc][0] * 0.25f + bv);
            h2t[(feat + 1) * TSTR + im] = sigf(acc[cc][1] * 0.25f + bv);
        }
    }

    // stage FC1 W tile 0 (writes wt: disjoint from h2t)
#pragma unroll
    for (int r = 0; r < 4; ++r) {
        const int idx = tid + 256 * r, row = idx >> 5, c4 = idx & 31;
        if (c4 < 30)
            *(float4*)(wt + row * 128 + c4 * 4) =
                *(const float4*)(L1 + row * 120 + c4 * 4);
    }
    __syncthreads();

    const int p = tid >> 5, jg = tid & 31;
    const int jc = jg < 30 ? jg : 29;

    // ---- FC1: 320 -> 120, 10 K-tiles of 32, double-buffered ----
    float acc[4][2];
    {
        union { float4 v; float f[4]; } bv;
        bv.v = *(const float4*)(Lb1 + jc * 4);
#pragma unroll
        for (int q = 0; q < 4; ++q) { acc[q][0] = bv.f[q]; acc[q][1] = bv.f[q]; }
    }
    int cur = 0;
    for (int t = 0; t < 10; ++t) {
        float4 wr0, wr1, wr2, wr3;
        if (t < 9) {
            const int k0n = (t + 1) * 32;
            const int c0 = tid & 31;
            wr0 = (c0 < 30) ? *(const float4*)(L1 + (k0n + (tid >> 5)) * 120 + c0 * 4) : make_float4(0, 0, 0, 0);
            wr1 = (c0 < 30) ? *(const float4*)(L1 + (k0n + ((tid + 256) >> 5)) * 120 + c0 * 4) : make_float4(0, 0, 0, 0);
            wr2 = (c0 < 30) ? *(const float4*)(L1 + (k0n + ((tid + 512) >> 5)) * 120 + c0 * 4) : make_float4(0, 0, 0, 0);
            wr3 = (c0 < 30) ? *(const float4*)(L1 + (k0n + ((tid + 768) >> 5)) * 120 + c0 * 4) : make_float4(0, 0, 0, 0);
        }
        const float* wb = wt + cur * 4096;
        const int kb = t * 32;
#pragma unroll
        for (int k = 0; k < 32; ++k) {
            union { float4 v; float f[4]; } w;
            w.v = *(const float4*)(wb + k * 128 + jc * 4);
            const float2 h = *(const float2*)&h2t[(kb + k) * TSTR + p * 2];
#pragma unroll
            for (int q = 0; q < 4; ++q) {
                acc[q][0] += w.f[q] * h.x;
                acc[q][1] += w.f[q] * h.y;
            }
        }
        if (t < 9) {
            float* wd = wt + (cur ^ 1) * 4096;
            const int c0 = tid & 31;
            if (c0 < 30) {
                *(float4*)(wd + (tid >> 5) * 128 + c0 * 4) = wr0;
                *(float4*)(wd + ((tid + 256) >> 5) * 128 + c0 * 4) = wr1;
                *(float4*)(wd + ((tid + 512) >> 5) * 128 + c0 * 4) = wr2;
                *(float4*)(wd + ((tid + 768) >> 5) * 128 + c0 * 4) = wr3;
            }
            cur ^= 1;
        }
        __syncthreads();
    }
    if (jg < 30) {
#pragma unroll
        for (int q = 0; q < 4; ++q) {
            g1t[(jg * 4 + q) * TSTR + p * 2 + 0] = sigf(acc[q][0]);
            g1t[(jg * 4 + q) * TSTR + p * 2 + 1] = sigf(acc[q][1]);
        }
    }
    __syncthreads();

    // ---- stage FC2 weights [120][88] at arena[0..10560) (dead h2t+wt;
    // ends before g1t@13952 -- r20 bug was overlapping live g1t) + L3/Lb3 ----
    float* w2s = arena;
    for (int i = tid; i < 2520; i += 256) {
        const int row = i / 21, c4 = i % 21;
        *(float4*)(w2s + row * 88 + c4 * 4) =
            *(const float4*)(L2 + row * 84 + c4 * 4);
    }
    for (int i = tid; i < 840; i += 256) L3s[i] = L3[i];
    if (tid < 10) L3s[840 + tid] = Lb3[tid];
    __syncthreads();

    // ---- FC2: 120 -> 84 ----
    if (jg < 21) {
        union { float4 v; float f[4]; } bv;
        bv.v = *(const float4*)(Lb2 + jg * 4);
        float a2[4][2];
#pragma unroll
        for (int q = 0; q < 4; ++q) { a2[q][0] = bv.f[q]; a2[q][1] = bv.f[q]; }
#pragma unroll 4
        for (int k = 0; k < 120; ++k) {
            union { float4 v; float f[4]; } w;
            w.v = *(const float4*)(w2s + k * 88 + jg * 4);
            const float2 h = *(const float2*)&g1t[k * TSTR + p * 2];
#pragma unroll
            for (int q = 0; q < 4; ++q) {
                a2[q][0] += w.f[q] * h.x;
                a2[q][1] += w.f[q] * h.y;
            }
        }
#pragma unroll
        for (int q = 0; q < 4; ++q) {
            g2t[(jg * 4 + q) * TSTR + p * 2 + 0] = sigf(a2[q][0]);
            g2t[(jg * 4 + q) * TSTR + p * 2 + 1] = sigf(a2[q][1]);
        }
    }
    __syncthreads();

    // ---- FC3: 84 -> 10 ----
    if (tid < 160) {
        const int im = tid / 10, j = tid % 10;
        float a = L3s[840 + j];
#pragma unroll 4
        for (int i = 0; i < 84; ++i)
            a += g2t[i * TSTR + im] * L3s[i * 10 + j];
        out[(img0 + im) * 10 + j] = a;
    }
}

extern "C" void kernel_launch(void* const* d_in, const int* in_sizes, int n_in,
                              void* d_out, int out_size, void* d_ws, size_t ws_size,
                              hipStream_t stream) {
    const float* x   = (const float*)d_in[0];
    const float* W1  = (const float*)d_in[1];
    const float* b1  = (const float*)d_in[2];
    const float* W2  = (const float*)d_in[3];
    const float* b2  = (const float*)d_in[4];
    const float* L1  = (const float*)d_in[5];
    const float* Lb1 = (const float*)d_in[6];
    const float* L2  = (const float*)d_in[7];
    const float* Lb2 = (const float*)d_in[8];
    const float* L3  = (const float*)d_in[9];
    const float* Lb3 = (const float*)d_in[10];
    float* out = (float*)d_out;

    const int B = in_sizes[0] / 784;  // 8192

    char* ws = (char*)d_ws;
    float* w6   = (float*)ws;                          // 1.9KB (pad 4KB)
    float* w2q  = (float*)(ws + 4096);                 // 20KB (pad 32KB)
    __half* S1h = (__half*)(ws + 4096 + 32768);        // B*1328*2 = 21.8MB

    hipLaunchKernelGGL(k_prep, dim3(22), dim3(256), 0, stream, W1, W2, w6, w2q);
    hipLaunchKernelGGL(k_conv1, dim3(B / 4), dim3(512), 0, stream, x, w6, b1, S1h);
    hipLaunchKernelGGL(k_fc, dim3(B / 16), dim3(256), 0, stream,
                       S1h, w2q, b2, L1, Lb1, L2, Lb2, L3, Lb3, out);
}

// Round 22
// 81.126 us; speedup vs baseline: 1.0795x; 1.0795x over previous
//
#include <hip/hip_runtime.h>
#include <hip/hip_fp16.h>
#include <math.h>

// LeNet-ish forward, fp32 compute, B=8192.
// conv1+pool = stride-2 6x6 conv (w6 = W1 (*) ones(2,2), /4 at use).
// S1 fp16 (r18); conv1 1-ch/thread (r19); r22: r21's fusion REVERTED
// (fused conv2 inherited low occupancy: 63us vs 40us separate). k_prep
// eliminated: conv1 folds W1->wq1 in-block; conv2 s_loads W2 directly
// (index remap keeps the address wave-uniform).
//
// ws: [S1h: B*1328 fp16][h2: B*320 f32]

__device__ __forceinline__ float sigf(float v) {
    return 1.0f / (1.0f + __expf(-v));
}

#define S1IM 1328  // per-image stride in halves (2656 B)

// --- K1: conv1(6x6 s2) + sigmoid + 2x2 window-sum -> S1h fp16.
// 512 thr = 8 waves = 4 images x 2 waves; wave w: im=w>>1, chbase=(w&1)*5.
// lane = (c<5, py<12). wq1 computed in-block from W1 (2x2 fold).
__global__ __launch_bounds__(512) void k_conv1(
    const float* __restrict__ x, const float* __restrict__ W1,
    const float* __restrict__ b1, __half* __restrict__ S1h) {
    __shared__ float4 XR[4 * 224];  // 14336 B, XOR-swizzled
    __shared__ float wq1[480];      // [ky6][ch10][kx8]
    __shared__ float bs1[10];

    const int tid = threadIdx.x;
    const long img0 = (long)blockIdx.x * 4;

    {
        const float4* xg = (const float4*)(x + img0 * 784);
        for (int i = tid; i < 784; i += 512) {
            int im = i / 196, j = i % 196, r = j / 7, kk = j % 7;
            XR[im * 224 + r * 8 + (kk ^ ((r >> 1) & 7))] = xg[i];
        }
    }
    if (tid < 480) {  // wq1[ky][c][kx] = sum_{dy,dx} W1[c][ky-dy][kx-dx]
        const int kx = tid & 7, t = tid >> 3, c = t % 10, ky = t / 10;
        float v = 0.f;
        if (kx < 6) {
#pragma unroll
            for (int dy = 0; dy < 2; ++dy)
#pragma unroll
                for (int dx = 0; dx < 2; ++dx) {
                    const int sy = ky - dy, sx = kx - dx;
                    if (sy >= 0 && sy < 5 && sx >= 0 && sx < 5)
                        v += W1[c * 25 + sy * 5 + sx];
                }
        }
        wq1[tid] = v;
    } else if (tid < 490) {
        bs1[tid - 480] = b1[tid - 480];
    }
    __syncthreads();

    const int w = tid >> 6, l = tid & 63;
    const int im = w >> 1, chbase = (w & 1) * 5;
    const long img = img0 + im;
    if (l < 60) {
        const int c = l / 12, py = l % 12;
        const int ch = chbase + c;
        float acc[12];
#pragma unroll
        for (int p = 0; p < 12; ++p) acc[p] = 0.f;

        const float4* xr = &XR[im * 224];
#pragma unroll
        for (int ky = 0; ky < 6; ++ky) {
            const int r = 2 * py + ky;
            const int hsh = (r >> 1) & 7;
            const int base = r * 8;
            union { float4 v[7]; float f[28]; } R;
#pragma unroll
            for (int q = 0; q < 7; ++q) R.v[q] = xr[base + (q ^ hsh)];
            union { float4 v[2]; float f[8]; } W;
            const float* wb = &wq1[(ky * 10 + ch) * 8];
            W.v[0] = *(const float4*)(wb);
            W.v[1] = *(const float4*)(wb + 4);
#pragma unroll
            for (int kx = 0; kx < 6; ++kx) {
                const float wv = W.f[kx];
#pragma unroll
                for (int px = 0; px < 12; ++px)
                    acc[px] += R.f[2 * px + kx] * wv;
            }
        }

        float h[12];
#pragma unroll
        for (int px = 0; px < 12; ++px)
            h[px] = sigf(acc[px] * 0.25f + bs1[ch]);
        float hh[11];
#pragma unroll
        for (int t = 0; t < 11; ++t) hh[t] = h[t] + h[t + 1];
        float o[12];
#pragma unroll
        for (int t = 0; t < 11; ++t)
            o[t] = hh[t] + __shfl_down(hh[t], 1, 64);  // (c, py+1): intra-wave
        o[11] = 0.f;
        if (py < 11) {
            union { __half hs[12]; uint2 u2[3]; } P;
#pragma unroll
            for (int t = 0; t < 12; ++t) P.hs[t] = __float2half(o[t]);
            __half* sp = S1h + img * S1IM + ch * 132 + py * 12;
            ((uint2*)sp)[0] = P.u2[0];
            ((uint2*)sp)[1] = P.u2[1];
            ((uint2*)sp)[2] = P.u2[2];
        }
    }
}

// --- K2: conv2 + pool + sigmoid. S1h -> h2[B][320].
// 320 thr = 5 independent waves (wave = cg), lane = (im3,py2,xh1), zero LDS.
// Weights s_loaded DIRECTLY from W2 (wave-uniform index; no repack needed).
// Block groups run in reverse order per XCD slot (freshest S1 first).
__global__ __launch_bounds__(320) void k_conv2(
    const __half* __restrict__ S1h, const float* __restrict__ W2,
    const float* __restrict__ b2, float* __restrict__ h2) {
    const int w = threadIdx.x >> 6, l = threadIdx.x & 63;
    const int cg = __builtin_amdgcn_readfirstlane(w);
    const int im = l >> 3, py = (l >> 1) & 3, xh = l & 1;
    const int grp = gridDim.x / 8;
    const int bidr = ((grp - 1 - ((int)blockIdx.x >> 3)) << 3) | ((int)blockIdx.x & 7);
    const long img0 = (long)bidr * 8;

    float acc[4][2];
#pragma unroll
    for (int a = 0; a < 4; ++a) { acc[a][0] = 0.f; acc[a][1] = 0.f; }

    const __half* s1 = S1h + (img0 + im) * S1IM;
    const float* wcg = W2 + (cg * 4) * 250;  // W2[c][ic][ky][kx], c=cg*4+cc
    for (int ic = 0; ic < 10; ++ic) {
#pragma unroll
        for (int ky = 0; ky < 5; ++ky) {
            const __half* rp = s1 + ic * 132 + (2 * py + ky) * 12 + xh * 4;
            union { uint2 u; __half2 h2v[2]; } A, B;
            A.u = *(const uint2*)(rp);
            B.u = *(const uint2*)(rp + 4);
            float R[8];
            float2 f0 = __half22float2(A.h2v[0]);
            float2 f1 = __half22float2(A.h2v[1]);
            float2 f2 = __half22float2(B.h2v[0]);
            float2 f3 = __half22float2(B.h2v[1]);
            R[0] = f0.x; R[1] = f0.y; R[2] = f1.x; R[3] = f1.y;
            R[4] = f2.x; R[5] = f2.y; R[6] = f3.x; R[7] = f3.y;
            const float* wrow = wcg + ic * 25 + ky * 5;
#pragma unroll
            for (int cc = 0; cc < 4; ++cc)
#pragma unroll
                for (int kx = 0; kx < 5; ++kx) {
                    const float wv = wrow[cc * 250 + kx];  // s_load (uniform)
                    acc[cc][0] += R[kx] * wv;
                    acc[cc][1] += R[2 + kx] * wv;
                }
        }
    }

    float* outp = h2 + (img0 + im) * 320 + (cg * 4) * 16 + py * 4 + xh * 2;
#pragma unroll
    for (int cc = 0; cc < 4; ++cc) {
        const float bv = b2[cg * 4 + cc];  // uniform s_load
        float2 o;
        o.x = sigf(acc[cc][0] * 0.25f + bv);
        o.y = sigf(acc[cc][1] * 0.25f + bv);
        *(float2*)(outp + cc * 16) = o;
    }
}

// --- K3: FC chain, GEMM-style with LDS-resident weights (r13/r19). ---
#define TSTR 18
__global__ __launch_bounds__(256) void k_fc(
    const float* __restrict__ h2, const float* __restrict__ L1,
    const float* __restrict__ Lb1, const float* __restrict__ L2,
    const float* __restrict__ Lb2, const float* __restrict__ L3,
    const float* __restrict__ Lb3, float* __restrict__ out) {
    __shared__ float arena[18480];   // 73920 B
    float* h2t = arena;              // [320][18]  = 5760   (FC1)
    float* wt  = arena + 5760;       // [2][32][128] = 8192 (FC1)
    float* g1t = arena + 13952;      // [120][18] = 2160
    float* g2t = arena + 16112;      // [84][18]  = 1512
    float* L3s = arena + 17624;      // 840 + 10
    // FC2 phase: w2s = arena[0..10560) (dead h2t+wt region)

    const int tid = threadIdx.x;
    const long img0 = (long)blockIdx.x * 16;

    for (int i = tid; i < 1280; i += 256) {
        const int im = i / 80, fq = i % 80;
        float4 v = *(const float4*)(h2 + (img0 + im) * 320 + fq * 4);
        h2t[(fq * 4 + 0) * TSTR + im] = v.x;
        h2t[(fq * 4 + 1) * TSTR + im] = v.y;
        h2t[(fq * 4 + 2) * TSTR + im] = v.z;
        h2t[(fq * 4 + 3) * TSTR + im] = v.w;
    }
#pragma unroll
    for (int r = 0; r < 4; ++r) {
        const int idx = tid + 256 * r, row = idx >> 5, c4 = idx & 31;
        if (c4 < 30)
            *(float4*)(wt + row * 128 + c4 * 4) =
                *(const float4*)(L1 + row * 120 + c4 * 4);
    }
    __syncthreads();

    const int p = tid >> 5, jg = tid & 31;
    const int jc = jg < 30 ? jg : 29;

    // ---- FC1: 320 -> 120, 10 K-tiles of 32, double-buffered ----
    float acc[4][2];
    {
        union { float4 v; float f[4]; } bv;
        bv.v = *(const float4*)(Lb1 + jc * 4);
#pragma unroll
        for (int q = 0; q < 4; ++q) { acc[q][0] = bv.f[q]; acc[q][1] = bv.f[q]; }
    }
    int cur = 0;
    for (int t = 0; t < 10; ++t) {
        float4 wr0, wr1, wr2, wr3;
        if (t < 9) {
            const int k0n = (t + 1) * 32;
            const int c0 = tid & 31;
            wr0 = (c0 < 30) ? *(const float4*)(L1 + (k0n + (tid >> 5)) * 120 + c0 * 4) : make_float4(0, 0, 0, 0);
            wr1 = (c0 < 30) ? *(const float4*)(L1 + (k0n + ((tid + 256) >> 5)) * 120 + c0 * 4) : make_float4(0, 0, 0, 0);
            wr2 = (c0 < 30) ? *(const float4*)(L1 + (k0n + ((tid + 512) >> 5)) * 120 + c0 * 4) : make_float4(0, 0, 0, 0);
            wr3 = (c0 < 30) ? *(const float4*)(L1 + (k0n + ((tid + 768) >> 5)) * 120 + c0 * 4) : make_float4(0, 0, 0, 0);
        }
        const float* wb = wt + cur * 4096;
        const int kb = t * 32;
#pragma unroll
        for (int k = 0; k < 32; ++k) {
            union { float4 v; float f[4]; } w;
            w.v = *(const float4*)(wb + k * 128 + jc * 4);
            const float2 h = *(const float2*)&h2t[(kb + k) * TSTR + p * 2];
#pragma unroll
            for (int q = 0; q < 4; ++q) {
                acc[q][0] += w.f[q] * h.x;
                acc[q][1] += w.f[q] * h.y;
            }
        }
        if (t < 9) {
            float* wd = wt + (cur ^ 1) * 4096;
            const int c0 = tid & 31;
            if (c0 < 30) {
                *(float4*)(wd + (tid >> 5) * 128 + c0 * 4) = wr0;
                *(float4*)(wd + ((tid + 256) >> 5) * 128 + c0 * 4) = wr1;
                *(float4*)(wd + ((tid + 512) >> 5) * 128 + c0 * 4) = wr2;
                *(float4*)(wd + ((tid + 768) >> 5) * 128 + c0 * 4) = wr3;
            }
            cur ^= 1;
        }
        __syncthreads();
    }
    if (jg < 30) {
#pragma unroll
        for (int q = 0; q < 4; ++q) {
            g1t[(jg * 4 + q) * TSTR + p * 2 + 0] = sigf(acc[q][0]);
            g1t[(jg * 4 + q) * TSTR + p * 2 + 1] = sigf(acc[q][1]);
        }
    }
    __syncthreads();

    // ---- stage FC2 weights [120][88] at arena[0..10560) + L3/Lb3 ----
    float* w2s = arena;
    for (int i = tid; i < 2520; i += 256) {
        const int row = i / 21, c4 = i % 21;
        *(float4*)(w2s + row * 88 + c4 * 4) =
            *(const float4*)(L2 + row * 84 + c4 * 4);
    }
    for (int i = tid; i < 840; i += 256) L3s[i] = L3[i];
    if (tid < 10) L3s[840 + tid] = Lb3[tid];
    __syncthreads();

    // ---- FC2: 120 -> 84 ----
    if (jg < 21) {
        union { float4 v; float f[4]; } bv;
        bv.v = *(const float4*)(Lb2 + jg * 4);
        float a2[4][2];
#pragma unroll
        for (int q = 0; q < 4; ++q) { a2[q][0] = bv.f[q]; a2[q][1] = bv.f[q]; }
#pragma unroll 4
        for (int k = 0; k < 120; ++k) {
            union { float4 v; float f[4]; } w;
            w.v = *(const float4*)(w2s + k * 88 + jg * 4);
            const float2 h = *(const float2*)&g1t[k * TSTR + p * 2];
#pragma unroll
            for (int q = 0; q < 4; ++q) {
                a2[q][0] += w.f[q] * h.x;
                a2[q][1] += w.f[q] * h.y;
            }
        }
#pragma unroll
        for (int q = 0; q < 4; ++q) {
            g2t[(jg * 4 + q) * TSTR + p * 2 + 0] = sigf(a2[q][0]);
            g2t[(jg * 4 + q) * TSTR + p * 2 + 1] = sigf(a2[q][1]);
        }
    }
    __syncthreads();

    // ---- FC3: 84 -> 10 ----
    if (tid < 160) {
        const int im = tid / 10, j = tid % 10;
        float a = L3s[840 + j];
#pragma unroll 4
        for (int i = 0; i < 84; ++i)
            a += g2t[i * TSTR + im] * L3s[i * 10 + j];
        out[(img0 + im) * 10 + j] = a;
    }
}

extern "C" void kernel_launch(void* const* d_in, const int* in_sizes, int n_in,
                              void* d_out, int out_size, void* d_ws, size_t ws_size,
                              hipStream_t stream) {
    const float* x   = (const float*)d_in[0];
    const float* W1  = (const float*)d_in[1];
    const float* b1  = (const float*)d_in[2];
    const float* W2  = (const float*)d_in[3];
    const float* b2  = (const float*)d_in[4];
    const float* L1  = (const float*)d_in[5];
    const float* Lb1 = (const float*)d_in[6];
    const float* L2  = (const float*)d_in[7];
    const float* Lb2 = (const float*)d_in[8];
    const float* L3  = (const float*)d_in[9];
    const float* Lb3 = (const float*)d_in[10];
    float* out = (float*)d_out;

    const int B = in_sizes[0] / 784;  // 8192

    char* ws = (char*)d_ws;
    __half* S1h = (__half*)ws;                         // B*1328*2 = 21.8MB
    float* h2   = (float*)(ws + (size_t)B * S1IM * 2);

    hipLaunchKernelGGL(k_conv1, dim3(B / 4), dim3(512), 0, stream, x, W1, b1, S1h);
    hipLaunchKernelGGL(k_conv2, dim3(B / 8), dim3(320), 0, stream, S1h, W2, b2, h2);
    hipLaunchKernelGGL(k_fc, dim3(B / 16), dim3(256), 0, stream,
                       h2, L1, Lb1, L2, Lb2, L3, Lb3, out);
}